// Round 1
// baseline (937.643 us; speedup 1.0000x reference)
//
#include <hip/hip_runtime.h>

#define NN 4096
#define HID 512
#define NH 8
#define HD 64

// ws layout (floats):
//   Q     [4096][512]  @ 0
//   K     [4096][512]  @ 2097152
//   V     [4096][512]  @ 4194304
//   Zpart [8][4096][32]@ 6291456
//   invZ  [8][4096]    @ 7340032
//   att   [4096][512]  @ 7372800
// total 9469952 floats = 37.9 MB

// ---------------- Kernel A: QKV projection -----------------
// grid (4, 32, 3), block 256. 128x128 tile, 8x8 micro (2x2 blocks of 4x4).
__global__ __launch_bounds__(256) void qkv_kernel(
    const float* __restrict__ x,
    const float* __restrict__ Wq, const float* __restrict__ bq,
    const float* __restrict__ Wk, const float* __restrict__ bk,
    const float* __restrict__ Wv, const float* __restrict__ bv,
    float* __restrict__ ws_out)
{
    const int mat = blockIdx.z;
    const float* W = (mat == 0) ? Wq : ((mat == 1) ? Wk : Wv);
    const float* b = (mat == 0) ? bq : ((mat == 1) ? bk : bv);
    float* O = ws_out + (size_t)mat * NN * HID;

    const int row0 = blockIdx.y * 128;
    const int col0 = blockIdx.x * 128;
    const int tid = threadIdx.x;
    const int tx = tid & 15, ty = tid >> 4;

    __shared__ float xs[32][132];   // [k][row] transposed
    __shared__ float wt[32][132];   // [k][col]

    float acc[8][8];
#pragma unroll
    for (int i = 0; i < 8; ++i)
#pragma unroll
        for (int j = 0; j < 8; ++j) acc[i][j] = 0.f;

    for (int kc = 0; kc < HID; kc += 32) {
        // x tile 128 rows x 32 k, transpose into LDS
#pragma unroll
        for (int it = 0; it < 4; ++it) {
            int f = it * 256 + tid;          // 1024 float4
            int i = f >> 3, k4 = f & 7;
            float4 v = *(const float4*)(x + (size_t)(row0 + i) * HID + kc + k4 * 4);
            xs[k4 * 4 + 0][i] = v.x; xs[k4 * 4 + 1][i] = v.y;
            xs[k4 * 4 + 2][i] = v.z; xs[k4 * 4 + 3][i] = v.w;
        }
        // W tile 32 k x 128 cols, direct
#pragma unroll
        for (int it = 0; it < 4; ++it) {
            int f = it * 256 + tid;          // 1024 float4
            int k = f >> 5, c4 = f & 31;
            float4 v = *(const float4*)(W + (size_t)(kc + k) * HID + col0 + c4 * 4);
            *(float4*)&wt[k][c4 * 4] = v;
        }
        __syncthreads();
        for (int k = 0; k < 32; ++k) {
            float a0[8], b0[8];
            *(float4*)&a0[0] = *(const float4*)&xs[k][ty * 4];
            *(float4*)&a0[4] = *(const float4*)&xs[k][64 + ty * 4];
            *(float4*)&b0[0] = *(const float4*)&wt[k][tx * 4];
            *(float4*)&b0[4] = *(const float4*)&wt[k][64 + tx * 4];
#pragma unroll
            for (int i = 0; i < 8; ++i)
#pragma unroll
                for (int j = 0; j < 8; ++j)
                    acc[i][j] = fmaf(a0[i], b0[j], acc[i][j]);
        }
        __syncthreads();
    }

#pragma unroll
    for (int bi = 0; bi < 2; ++bi)
#pragma unroll
        for (int ii = 0; ii < 4; ++ii) {
            int r = row0 + bi * 64 + ty * 4 + ii;
#pragma unroll
            for (int bj = 0; bj < 2; ++bj) {
                int c = col0 + bj * 64 + tx * 4;
                float4 v;
                v.x = acc[bi * 4 + ii][bj * 4 + 0] + b[c + 0];
                v.y = acc[bi * 4 + ii][bj * 4 + 1] + b[c + 1];
                v.z = acc[bi * 4 + ii][bj * 4 + 2] + b[c + 2];
                v.w = acc[bi * 4 + ii][bj * 4 + 3] + b[c + 3];
                *(float4*)(O + (size_t)r * HID + c) = v;
            }
        }
}

// ---------------- Kernel B1: S = exp(QK^T/8), unnormalized ----------------
// grid (32, 32, 8), block 256. 128x128 tile per head.
__global__ __launch_bounds__(256) void scores_kernel(
    const float* __restrict__ Q, const float* __restrict__ K,
    float* __restrict__ wout, float* __restrict__ Zpart)
{
    const int h = blockIdx.z;
    const int row0 = blockIdx.y * 128;
    const int col0 = blockIdx.x * 128;
    const int tid = threadIdx.x;
    const int tx = tid & 15, ty = tid >> 4;

    __shared__ float qs[32][132];
    __shared__ float ks[32][132];
    __shared__ float part[128][16];

    float acc[8][8];
#pragma unroll
    for (int i = 0; i < 8; ++i)
#pragma unroll
        for (int j = 0; j < 8; ++j) acc[i][j] = 0.f;

    for (int kc = 0; kc < HD; kc += 32) {
#pragma unroll
        for (int it = 0; it < 4; ++it) {
            int f = it * 256 + tid;
            int i = f >> 3, k4 = f & 7;
            float4 v = *(const float4*)(Q + (size_t)(row0 + i) * HID + h * HD + kc + k4 * 4);
            qs[k4 * 4 + 0][i] = v.x; qs[k4 * 4 + 1][i] = v.y;
            qs[k4 * 4 + 2][i] = v.z; qs[k4 * 4 + 3][i] = v.w;
        }
#pragma unroll
        for (int it = 0; it < 4; ++it) {
            int f = it * 256 + tid;
            int i = f >> 3, k4 = f & 7;
            float4 v = *(const float4*)(K + (size_t)(col0 + i) * HID + h * HD + kc + k4 * 4);
            ks[k4 * 4 + 0][i] = v.x; ks[k4 * 4 + 1][i] = v.y;
            ks[k4 * 4 + 2][i] = v.z; ks[k4 * 4 + 3][i] = v.w;
        }
        __syncthreads();
        for (int k = 0; k < 32; ++k) {
            float a0[8], b0[8];
            *(float4*)&a0[0] = *(const float4*)&qs[k][ty * 4];
            *(float4*)&a0[4] = *(const float4*)&qs[k][64 + ty * 4];
            *(float4*)&b0[0] = *(const float4*)&ks[k][tx * 4];
            *(float4*)&b0[4] = *(const float4*)&ks[k][64 + tx * 4];
#pragma unroll
            for (int i = 0; i < 8; ++i)
#pragma unroll
                for (int j = 0; j < 8; ++j)
                    acc[i][j] = fmaf(a0[i], b0[j], acc[i][j]);
        }
        __syncthreads();
    }

    float* WH = wout + ((size_t)h << 24);
#pragma unroll
    for (int bi = 0; bi < 2; ++bi)
#pragma unroll
        for (int ii = 0; ii < 4; ++ii) {
            int rl = bi * 64 + ty * 4 + ii;
            int r = row0 + rl;
            float rs = 0.f;
#pragma unroll
            for (int bj = 0; bj < 2; ++bj) {
                int c = col0 + bj * 64 + tx * 4;
                float4 v;
                v.x = __expf(acc[bi * 4 + ii][bj * 4 + 0] * 0.125f);
                v.y = __expf(acc[bi * 4 + ii][bj * 4 + 1] * 0.125f);
                v.z = __expf(acc[bi * 4 + ii][bj * 4 + 2] * 0.125f);
                v.w = __expf(acc[bi * 4 + ii][bj * 4 + 3] * 0.125f);
                *(float4*)(WH + (size_t)r * NN + c) = v;
                rs += v.x + v.y + v.z + v.w;
            }
            part[rl][tx] = rs;
        }
    __syncthreads();
    if (tid < 128) {
        float z = 0.f;
#pragma unroll
        for (int t = 0; t < 16; ++t) z += part[tid][t];
        Zpart[((size_t)h * NN + row0 + tid) * 32 + blockIdx.x] = z;
    }
}

// ---------------- Kernel Bz: invZ ----------------
__global__ __launch_bounds__(256) void zred_kernel(
    const float* __restrict__ Zpart, float* __restrict__ invZ)
{
    int idx = blockIdx.x * 256 + threadIdx.x;   // 0..32767
    const float* p = Zpart + (size_t)idx * 32;
    float s = 0.f;
#pragma unroll
    for (int t = 0; t < 32; ++t) s += p[t];
    invZ[idx] = 1.0f / s;
}

// ---------------- Kernel B2: normalize P (in place) + attended = P@V ----------------
// grid (32, 8), block 256. 128 rows x 64 dims per WG, K=4096 in chunks of 64.
__global__ __launch_bounds__(256) void pv_kernel(
    float* __restrict__ wout, const float* __restrict__ invZ,
    const float* __restrict__ V, float* __restrict__ att)
{
    const int h = blockIdx.y;
    const int row0 = blockIdx.x * 128;
    const int tid = threadIdx.x;
    const int tx = tid & 15, ty = tid >> 4;

    __shared__ float ps[64][132];   // [k][row]
    __shared__ float vs[64][68];    // [k][d]
    __shared__ float iz[128];

    if (tid < 128) iz[tid] = invZ[(size_t)h * NN + row0 + tid];
    __syncthreads();

    float acc[8][4];
#pragma unroll
    for (int i = 0; i < 8; ++i)
#pragma unroll
        for (int j = 0; j < 4; ++j) acc[i][j] = 0.f;

    float* WH = wout + ((size_t)h << 24);

    for (int nc = 0; nc < NN; nc += 64) {
        // P chunk 128 rows x 64 n : load, normalize, write back, transpose into LDS
#pragma unroll
        for (int it = 0; it < 8; ++it) {
            int f = it * 256 + tid;          // 2048 float4
            int i = f >> 4, k4 = f & 15;
            float* gp = WH + (size_t)(row0 + i) * NN + nc + k4 * 4;
            float4 v = *(float4*)gp;
            float s = iz[i];
            v.x *= s; v.y *= s; v.z *= s; v.w *= s;
            *(float4*)gp = v;
            ps[k4 * 4 + 0][i] = v.x; ps[k4 * 4 + 1][i] = v.y;
            ps[k4 * 4 + 2][i] = v.z; ps[k4 * 4 + 3][i] = v.w;
        }
        // V chunk 64 n x 64 d, direct
#pragma unroll
        for (int it = 0; it < 4; ++it) {
            int f = it * 256 + tid;          // 1024 float4
            int k = f >> 4, d4 = f & 15;
            float4 v = *(const float4*)(V + (size_t)(nc + k) * HID + h * HD + d4 * 4);
            *(float4*)&vs[k][d4 * 4] = v;
        }
        __syncthreads();
        for (int k = 0; k < 64; ++k) {
            float a0[8], b0[4];
            *(float4*)&a0[0] = *(const float4*)&ps[k][ty * 8];
            *(float4*)&a0[4] = *(const float4*)&ps[k][ty * 8 + 4];
            *(float4*)&b0[0] = *(const float4*)&vs[k][tx * 4];
#pragma unroll
            for (int i = 0; i < 8; ++i)
#pragma unroll
                for (int j = 0; j < 4; ++j)
                    acc[i][j] = fmaf(a0[i], b0[j], acc[i][j]);
        }
        __syncthreads();
    }

#pragma unroll
    for (int ii = 0; ii < 8; ++ii) {
        int r = row0 + ty * 8 + ii;
        float4 v;
        v.x = acc[ii][0]; v.y = acc[ii][1]; v.z = acc[ii][2]; v.w = acc[ii][3];
        *(float4*)(att + (size_t)r * HID + h * HD + tx * 4) = v;
    }
}

// ---------------- Kernel C: output = att @ Wo + bo ----------------
// grid (64), block 256. 64 rows x 64 cols tile, K=512 in chunks of 64.
__global__ __launch_bounds__(256) void out_kernel(
    const float* __restrict__ att, const float* __restrict__ Wo,
    const float* __restrict__ bo, float* __restrict__ outp)
{
    const int row0 = blockIdx.x * 64;
    const int tid = threadIdx.x;
    const int tx = tid & 15, ty = tid >> 4;

    __shared__ float as_[64][68];   // [k][row]
    __shared__ float ws2[64][68];   // [k][col]

    float acc[4][4];
#pragma unroll
    for (int i = 0; i < 4; ++i)
#pragma unroll
        for (int j = 0; j < 4; ++j) acc[i][j] = 0.f;

    for (int kc = 0; kc < HID; kc += 64) {
#pragma unroll
        for (int it = 0; it < 4; ++it) {
            int f = it * 256 + tid;          // 1024 float4
            int i = f >> 4, k4 = f & 15;
            float4 v = *(const float4*)(att + (size_t)(row0 + i) * HID + kc + k4 * 4);
            as_[k4 * 4 + 0][i] = v.x; as_[k4 * 4 + 1][i] = v.y;
            as_[k4 * 4 + 2][i] = v.z; as_[k4 * 4 + 3][i] = v.w;
        }
#pragma unroll
        for (int it = 0; it < 4; ++it) {
            int f = it * 256 + tid;          // 1024 float4
            int k = f >> 4, c4 = f & 15;
            float4 v = *(const float4*)(Wo + (size_t)(kc + k) * HD + c4 * 4);
            *(float4*)&ws2[k][c4 * 4] = v;
        }
        __syncthreads();
        for (int k = 0; k < 64; ++k) {
            float a0[4], b0[4];
            *(float4*)&a0[0] = *(const float4*)&as_[k][ty * 4];
            *(float4*)&b0[0] = *(const float4*)&ws2[k][tx * 4];
#pragma unroll
            for (int i = 0; i < 4; ++i)
#pragma unroll
                for (int j = 0; j < 4; ++j)
                    acc[i][j] = fmaf(a0[i], b0[j], acc[i][j]);
        }
        __syncthreads();
    }

#pragma unroll
    for (int ii = 0; ii < 4; ++ii) {
        int r = row0 + ty * 4 + ii;
        float4 v;
        v.x = acc[ii][0] + bo[tx * 4 + 0];
        v.y = acc[ii][1] + bo[tx * 4 + 1];
        v.z = acc[ii][2] + bo[tx * 4 + 2];
        v.w = acc[ii][3] + bo[tx * 4 + 3];
        *(float4*)(outp + (size_t)r * HD + tx * 4) = v;
    }
}

extern "C" void kernel_launch(void* const* d_in, const int* in_sizes, int n_in,
                              void* d_out, int out_size, void* d_ws, size_t ws_size,
                              hipStream_t stream) {
    const float* x  = (const float*)d_in[0];
    const float* Wq = (const float*)d_in[1];
    const float* bq = (const float*)d_in[2];
    const float* Wk = (const float*)d_in[3];
    const float* bk = (const float*)d_in[4];
    const float* Wv = (const float*)d_in[5];
    const float* bv = (const float*)d_in[6];
    const float* Wo = (const float*)d_in[7];
    const float* bo = (const float*)d_in[8];

    float* out = (float*)d_out;
    float* ws  = (float*)d_ws;

    float* Q     = ws;
    float* K     = ws + 2097152;
    float* V     = ws + 4194304;
    float* Zpart = ws + 6291456;
    float* invZ  = ws + 7340032;
    float* att   = ws + 7372800;
    float* wout  = out + (size_t)NN * HD;   // attention weights region

    hipLaunchKernelGGL(qkv_kernel, dim3(4, 32, 3), dim3(256), 0, stream,
                       x, Wq, bq, Wk, bk, Wv, bv, ws);
    hipLaunchKernelGGL(scores_kernel, dim3(32, 32, 8), dim3(256), 0, stream,
                       Q, K, wout, Zpart);
    hipLaunchKernelGGL(zred_kernel, dim3(128), dim3(256), 0, stream,
                       Zpart, invZ);
    hipLaunchKernelGGL(pv_kernel, dim3(32, 8), dim3(256), 0, stream,
                       wout, invZ, V, att);
    hipLaunchKernelGGL(out_kernel, dim3(64), dim3(256), 0, stream,
                       att, Wo, bo, out);
}

// Round 2
// 565.088 us; speedup vs baseline: 1.6593x; 1.6593x over previous
//
#include <hip/hip_runtime.h>

#define NN 4096
#define HID 512
#define NH 8
#define HD 64

typedef __attribute__((ext_vector_type(8))) short short8;
typedef __attribute__((ext_vector_type(4))) float f32x4;

__device__ __forceinline__ ushort f2bf(float f) {
    unsigned u = __float_as_uint(f);
    return (ushort)((u + 0x7FFFu + ((u >> 16) & 1u)) >> 16);   // RNE
}

// ---------------- Kernel A: QKV projection (f32 compute, bf16 output) -----------------
// grid (4, 32, 3), block 256. 128x128 tile, 8x8 micro.
// mat 0 -> Qb[h][n][64] bf16, mat 1 -> Kb[h][n][64] bf16, mat 2 -> Vt[c][n] bf16 (c = h*64+d).
__global__ __launch_bounds__(256) void qkv_kernel(
    const float* __restrict__ x,
    const float* __restrict__ Wq, const float* __restrict__ bq,
    const float* __restrict__ Wk, const float* __restrict__ bk,
    const float* __restrict__ Wv, const float* __restrict__ bv,
    ushort* __restrict__ Qb, ushort* __restrict__ Kb, ushort* __restrict__ Vt)
{
    const int mat = blockIdx.z;
    const float* W = (mat == 0) ? Wq : ((mat == 1) ? Wk : Wv);
    const float* b = (mat == 0) ? bq : ((mat == 1) ? bk : bv);

    const int row0 = blockIdx.y * 128;
    const int col0 = blockIdx.x * 128;
    const int tid = threadIdx.x;
    const int tx = tid & 15, ty = tid >> 4;

    __shared__ float xs[32][132];   // [k][row] transposed
    __shared__ float wt[32][132];   // [k][col]
    __shared__ __align__(16) ushort vts[128][136];  // V transpose staging [c_local][r_local]

    float acc[8][8];
#pragma unroll
    for (int i = 0; i < 8; ++i)
#pragma unroll
        for (int j = 0; j < 8; ++j) acc[i][j] = 0.f;

    for (int kc = 0; kc < HID; kc += 32) {
#pragma unroll
        for (int it = 0; it < 4; ++it) {
            int f = it * 256 + tid;
            int i = f >> 3, k4 = f & 7;
            float4 v = *(const float4*)(x + (size_t)(row0 + i) * HID + kc + k4 * 4);
            xs[k4 * 4 + 0][i] = v.x; xs[k4 * 4 + 1][i] = v.y;
            xs[k4 * 4 + 2][i] = v.z; xs[k4 * 4 + 3][i] = v.w;
        }
#pragma unroll
        for (int it = 0; it < 4; ++it) {
            int f = it * 256 + tid;
            int k = f >> 5, c4 = f & 31;
            float4 v = *(const float4*)(W + (size_t)(kc + k) * HID + col0 + c4 * 4);
            *(float4*)&wt[k][c4 * 4] = v;
        }
        __syncthreads();
        for (int k = 0; k < 32; ++k) {
            float a0[8], b0[8];
            *(float4*)&a0[0] = *(const float4*)&xs[k][ty * 4];
            *(float4*)&a0[4] = *(const float4*)&xs[k][64 + ty * 4];
            *(float4*)&b0[0] = *(const float4*)&wt[k][tx * 4];
            *(float4*)&b0[4] = *(const float4*)&wt[k][64 + tx * 4];
#pragma unroll
            for (int i = 0; i < 8; ++i)
#pragma unroll
                for (int j = 0; j < 8; ++j)
                    acc[i][j] = fmaf(a0[i], b0[j], acc[i][j]);
        }
        __syncthreads();
    }

    if (mat < 2) {
        ushort* O = (mat == 0) ? Qb : Kb;
#pragma unroll
        for (int bi = 0; bi < 2; ++bi)
#pragma unroll
            for (int ii = 0; ii < 4; ++ii) {
                int r = row0 + bi * 64 + ty * 4 + ii;
#pragma unroll
                for (int bj = 0; bj < 2; ++bj) {
                    int c = col0 + bj * 64 + tx * 4;
                    ushort4 u;
                    u.x = f2bf(acc[bi * 4 + ii][bj * 4 + 0] + b[c + 0]);
                    u.y = f2bf(acc[bi * 4 + ii][bj * 4 + 1] + b[c + 1]);
                    u.z = f2bf(acc[bi * 4 + ii][bj * 4 + 2] + b[c + 2]);
                    u.w = f2bf(acc[bi * 4 + ii][bj * 4 + 3] + b[c + 3]);
                    // head h = c>>6, d = c&63 : Qb[(h*NN + r)*HD + d]
                    *(ushort4*)(O + ((size_t)(c >> 6) * NN + r) * HD + (c & 63)) = u;
                }
            }
    } else {
        // V: stage bf16 transposed tile in LDS, then write Vt[c][r] coalesced per c-row.
#pragma unroll
        for (int bi = 0; bi < 2; ++bi)
#pragma unroll
            for (int ii = 0; ii < 4; ++ii) {
                int rl = bi * 64 + ty * 4 + ii;
#pragma unroll
                for (int bj = 0; bj < 2; ++bj)
#pragma unroll
                    for (int j = 0; j < 4; ++j) {
                        int cl = bj * 64 + tx * 4 + j;
                        vts[cl][rl] = f2bf(acc[bi * 4 + ii][bj * 4 + j] + b[col0 + cl]);
                    }
            }
        __syncthreads();
        int cl = tid >> 1, hf = tid & 1;
        const ushort* src = &vts[cl][hf * 64];
        ushort* dst = Vt + (size_t)(col0 + cl) * NN + row0 + hf * 64;
#pragma unroll
        for (int k = 0; k < 8; ++k)
            *(uint4*)(dst + k * 8) = *(const uint4*)(src + k * 8);
    }
}

// ---------------- Kernel B: fused attention ----------------
// grid (64, 8), block 256 (4 waves, 16 rows/wave).
// Pass A: Z = sum_j exp(q.k/8) via MFMA (no weight write).
// Pass B: recompute scores, write normalized weights once, P@V via MFMA.
__global__ __launch_bounds__(256) void attn_kernel(
    const ushort* __restrict__ Qb, const ushort* __restrict__ Kb,
    const ushort* __restrict__ Vt,
    float* __restrict__ wout, float* __restrict__ att)
{
    const int h = blockIdx.y;
    const int row0 = blockIdx.x * 64;
    const int tid = threadIdx.x;
    const int w = tid >> 6, lane = tid & 63;
    const int g = lane >> 4, li = lane & 15;
    const int rbase = row0 + w * 16;

    const ushort* Qh = Qb + (size_t)h * NN * HD;
    const ushort* Kh = Kb + (size_t)h * NN * HD;
    const ushort* Vh = Vt + (size_t)h * HD * NN;
    float* WH = wout + ((size_t)h << 24);

    __shared__ __align__(16) char pbytes[4][2048];   // per-wave 16x64 bf16 P tile, XOR-swizzled

    // Q fragments: A[m=li][k=g*8+j], k-blocks 0 and 1 (d=0..31, 32..63)
    const short8 qa0 = *(const short8*)(Qh + (size_t)(rbase + li) * HD + g * 8);
    const short8 qa1 = *(const short8*)(Qh + (size_t)(rbase + li) * HD + 32 + g * 8);

    // ---- Pass A: row sums of exp ----
    float zacc[4] = {0.f, 0.f, 0.f, 0.f};
#pragma unroll 4
    for (int jt = 0; jt < 256; ++jt) {
        const ushort* kp = Kh + (size_t)(jt * 16 + li) * HD + g * 8;
        short8 kb0 = *(const short8*)(kp);
        short8 kb1 = *(const short8*)(kp + 32);
        f32x4 acc = {0.f, 0.f, 0.f, 0.f};
        acc = __builtin_amdgcn_mfma_f32_16x16x32_bf16(qa0, kb0, acc, 0, 0, 0);
        acc = __builtin_amdgcn_mfma_f32_16x16x32_bf16(qa1, kb1, acc, 0, 0, 0);
#pragma unroll
        for (int r = 0; r < 4; ++r) zacc[r] += __expf(acc[r] * 0.125f);
    }
#pragma unroll
    for (int m = 1; m < 16; m <<= 1)
#pragma unroll
        for (int r = 0; r < 4; ++r) zacc[r] += __shfl_xor(zacc[r], m);
    float iz[4];
#pragma unroll
    for (int r = 0; r < 4; ++r) iz[r] = 1.0f / zacc[r];

    // ---- Pass B: weights write + P@V ----
    f32x4 pv[4];
#pragma unroll
    for (int dt = 0; dt < 4; ++dt) pv[dt] = (f32x4){0.f, 0.f, 0.f, 0.f};

    char* myp = pbytes[w];
    for (int nc = 0; nc < NN; nc += 64) {
        __syncthreads();   // protect LDS WAR vs previous chunk's reads
#pragma unroll
        for (int jj = 0; jj < 4; ++jj) {
            int jt = (nc >> 4) + jj;
            const ushort* kp = Kh + (size_t)(jt * 16 + li) * HD + g * 8;
            short8 kb0 = *(const short8*)(kp);
            short8 kb1 = *(const short8*)(kp + 32);
            f32x4 acc = {0.f, 0.f, 0.f, 0.f};
            acc = __builtin_amdgcn_mfma_f32_16x16x32_bf16(qa0, kb0, acc, 0, 0, 0);
            acc = __builtin_amdgcn_mfma_f32_16x16x32_bf16(qa1, kb1, acc, 0, 0, 0);
#pragma unroll
            for (int r = 0; r < 4; ++r) {
                float e = __expf(acc[r] * 0.125f) * iz[r];
                int row = g * 4 + r;
                WH[(size_t)(rbase + row) * NN + nc + jj * 16 + li] = e;
                int byteoff = (row * 128 + (jj * 16 + li) * 2) ^ ((row & 7) << 4);
                *(ushort*)(myp + byteoff) = f2bf(e);
            }
        }
        __syncthreads();   // P tile visible before A-frag reads
#pragma unroll
        for (int kb = 0; kb < 2; ++kb) {
            int rbyte = (li * 128 + kb * 64 + g * 16) ^ ((li & 7) << 4);
            short8 pa = *(const short8*)(myp + rbyte);
            const ushort* vp = Vh + nc + kb * 32 + g * 8;
#pragma unroll
            for (int dt = 0; dt < 4; ++dt) {
                short8 vb = *(const short8*)(vp + (size_t)(dt * 16 + li) * NN);
                pv[dt] = __builtin_amdgcn_mfma_f32_16x16x32_bf16(pa, vb, pv[dt], 0, 0, 0);
            }
        }
    }

#pragma unroll
    for (int dt = 0; dt < 4; ++dt)
#pragma unroll
        for (int r = 0; r < 4; ++r)
            att[(size_t)(rbase + g * 4 + r) * HID + h * HD + dt * 16 + li] = pv[dt][r];
}

// ---------------- Kernel C: output = att @ Wo + bo ----------------
__global__ __launch_bounds__(256) void out_kernel(
    const float* __restrict__ att, const float* __restrict__ Wo,
    const float* __restrict__ bo, float* __restrict__ outp)
{
    const int row0 = blockIdx.x * 64;
    const int tid = threadIdx.x;
    const int tx = tid & 15, ty = tid >> 4;

    __shared__ float as_[64][68];
    __shared__ float ws2[64][68];

    float acc[4][4];
#pragma unroll
    for (int i = 0; i < 4; ++i)
#pragma unroll
        for (int j = 0; j < 4; ++j) acc[i][j] = 0.f;

    for (int kc = 0; kc < HID; kc += 64) {
#pragma unroll
        for (int it = 0; it < 4; ++it) {
            int f = it * 256 + tid;
            int i = f >> 4, k4 = f & 15;
            float4 v = *(const float4*)(att + (size_t)(row0 + i) * HID + kc + k4 * 4);
            as_[k4 * 4 + 0][i] = v.x; as_[k4 * 4 + 1][i] = v.y;
            as_[k4 * 4 + 2][i] = v.z; as_[k4 * 4 + 3][i] = v.w;
        }
#pragma unroll
        for (int it = 0; it < 4; ++it) {
            int f = it * 256 + tid;
            int k = f >> 4, c4 = f & 15;
            float4 v = *(const float4*)(Wo + (size_t)(kc + k) * HD + c4 * 4);
            *(float4*)&ws2[k][c4 * 4] = v;
        }
        __syncthreads();
        for (int k = 0; k < 64; ++k) {
            float a0[4], b0[4];
            *(float4*)&a0[0] = *(const float4*)&as_[k][ty * 4];
            *(float4*)&b0[0] = *(const float4*)&ws2[k][tx * 4];
#pragma unroll
            for (int i = 0; i < 4; ++i)
#pragma unroll
                for (int j = 0; j < 4; ++j)
                    acc[i][j] = fmaf(a0[i], b0[j], acc[i][j]);
        }
        __syncthreads();
    }

#pragma unroll
    for (int ii = 0; ii < 4; ++ii) {
        int r = row0 + ty * 4 + ii;
        float4 v;
        v.x = acc[ii][0] + bo[tx * 4 + 0];
        v.y = acc[ii][1] + bo[tx * 4 + 1];
        v.z = acc[ii][2] + bo[tx * 4 + 2];
        v.w = acc[ii][3] + bo[tx * 4 + 3];
        *(float4*)(outp + (size_t)r * HD + tx * 4) = v;
    }
}

extern "C" void kernel_launch(void* const* d_in, const int* in_sizes, int n_in,
                              void* d_out, int out_size, void* d_ws, size_t ws_size,
                              hipStream_t stream) {
    const float* x  = (const float*)d_in[0];
    const float* Wq = (const float*)d_in[1];
    const float* bq = (const float*)d_in[2];
    const float* Wk = (const float*)d_in[3];
    const float* bk = (const float*)d_in[4];
    const float* Wv = (const float*)d_in[5];
    const float* bv = (const float*)d_in[6];
    const float* Wo = (const float*)d_in[7];
    const float* bo = (const float*)d_in[8];

    float* out  = (float*)d_out;
    float* wout = out + (size_t)NN * HD;      // attention-weights output region

    char* wsb = (char*)d_ws;
    ushort* Qb = (ushort*)wsb;                           // 4 MB
    ushort* Kb = Qb + (size_t)NH * NN * HD;              // 4 MB
    ushort* Vt = Kb + (size_t)NH * NN * HD;              // 4 MB
    float*  att = (float*)(wsb + 12u * 1024u * 1024u);   // 8 MB

    hipLaunchKernelGGL(qkv_kernel, dim3(4, 32, 3), dim3(256), 0, stream,
                       x, Wq, bq, Wk, bk, Wv, bv, Qb, Kb, Vt);
    hipLaunchKernelGGL(attn_kernel, dim3(64, NH), dim3(256), 0, stream,
                       Qb, Kb, Vt, wout, att);
    hipLaunchKernelGGL(out_kernel, dim3(64), dim3(256), 0, stream,
                       att, Wo, bo, out);
}

// Round 3
// 477.707 us; speedup vs baseline: 1.9628x; 1.1829x over previous
//
#include <hip/hip_runtime.h>

#define NN 4096
#define HID 512
#define NH 8
#define HD 64

typedef __attribute__((ext_vector_type(8))) short short8;
typedef __attribute__((ext_vector_type(4))) float f32x4;

__device__ __forceinline__ ushort f2bf(float f) {
    unsigned u = __float_as_uint(f);
    return (ushort)((u + 0x7FFFu + ((u >> 16) & 1u)) >> 16);   // RNE
}

// ---------------- Kernel A: QKV projection (f32 compute, bf16 output) -----------------
// grid (4, 32, 3), block 256. 128x128 tile, 8x8 micro.
// mat 0 -> Qb[h][n][64] bf16, mat 1 -> Kb[h][n][64] bf16, mat 2 -> Vt[c][n] bf16 (c = h*64+d).
__global__ __launch_bounds__(256) void qkv_kernel(
    const float* __restrict__ x,
    const float* __restrict__ Wq, const float* __restrict__ bq,
    const float* __restrict__ Wk, const float* __restrict__ bk,
    const float* __restrict__ Wv, const float* __restrict__ bv,
    ushort* __restrict__ Qb, ushort* __restrict__ Kb, ushort* __restrict__ Vt)
{
    const int mat = blockIdx.z;
    const float* W = (mat == 0) ? Wq : ((mat == 1) ? Wk : Wv);
    const float* b = (mat == 0) ? bq : ((mat == 1) ? bk : bv);

    const int row0 = blockIdx.y * 128;
    const int col0 = blockIdx.x * 128;
    const int tid = threadIdx.x;
    const int tx = tid & 15, ty = tid >> 4;

    __shared__ float xs[32][132];   // [k][row] transposed
    __shared__ float wt[32][132];   // [k][col]
    __shared__ __align__(16) ushort vts[128][136];  // V transpose staging [c_local][r_local]

    float acc[8][8];
#pragma unroll
    for (int i = 0; i < 8; ++i)
#pragma unroll
        for (int j = 0; j < 8; ++j) acc[i][j] = 0.f;

    for (int kc = 0; kc < HID; kc += 32) {
#pragma unroll
        for (int it = 0; it < 4; ++it) {
            int f = it * 256 + tid;
            int i = f >> 3, k4 = f & 7;
            float4 v = *(const float4*)(x + (size_t)(row0 + i) * HID + kc + k4 * 4);
            xs[k4 * 4 + 0][i] = v.x; xs[k4 * 4 + 1][i] = v.y;
            xs[k4 * 4 + 2][i] = v.z; xs[k4 * 4 + 3][i] = v.w;
        }
#pragma unroll
        for (int it = 0; it < 4; ++it) {
            int f = it * 256 + tid;
            int k = f >> 5, c4 = f & 31;
            float4 v = *(const float4*)(W + (size_t)(kc + k) * HID + col0 + c4 * 4);
            *(float4*)&wt[k][c4 * 4] = v;
        }
        __syncthreads();
        for (int k = 0; k < 32; ++k) {
            float a0[8], b0[8];
            *(float4*)&a0[0] = *(const float4*)&xs[k][ty * 4];
            *(float4*)&a0[4] = *(const float4*)&xs[k][64 + ty * 4];
            *(float4*)&b0[0] = *(const float4*)&wt[k][tx * 4];
            *(float4*)&b0[4] = *(const float4*)&wt[k][64 + tx * 4];
#pragma unroll
            for (int i = 0; i < 8; ++i)
#pragma unroll
                for (int j = 0; j < 8; ++j)
                    acc[i][j] = fmaf(a0[i], b0[j], acc[i][j]);
        }
        __syncthreads();
    }

    if (mat < 2) {
        ushort* O = (mat == 0) ? Qb : Kb;
#pragma unroll
        for (int bi = 0; bi < 2; ++bi)
#pragma unroll
            for (int ii = 0; ii < 4; ++ii) {
                int r = row0 + bi * 64 + ty * 4 + ii;
#pragma unroll
                for (int bj = 0; bj < 2; ++bj) {
                    int c = col0 + bj * 64 + tx * 4;
                    ushort4 u;
                    u.x = f2bf(acc[bi * 4 + ii][bj * 4 + 0] + b[c + 0]);
                    u.y = f2bf(acc[bi * 4 + ii][bj * 4 + 1] + b[c + 1]);
                    u.z = f2bf(acc[bi * 4 + ii][bj * 4 + 2] + b[c + 2]);
                    u.w = f2bf(acc[bi * 4 + ii][bj * 4 + 3] + b[c + 3]);
                    *(ushort4*)(O + ((size_t)(c >> 6) * NN + r) * HD + (c & 63)) = u;
                }
            }
    } else {
#pragma unroll
        for (int bi = 0; bi < 2; ++bi)
#pragma unroll
            for (int ii = 0; ii < 4; ++ii) {
                int rl = bi * 64 + ty * 4 + ii;
#pragma unroll
                for (int bj = 0; bj < 2; ++bj)
#pragma unroll
                    for (int j = 0; j < 4; ++j) {
                        int cl = bj * 64 + tx * 4 + j;
                        vts[cl][rl] = f2bf(acc[bi * 4 + ii][bj * 4 + j] + b[col0 + cl]);
                    }
            }
        __syncthreads();
        int cl = tid >> 1, hf = tid & 1;
        const ushort* src = &vts[cl][hf * 64];
        ushort* dst = Vt + (size_t)(col0 + cl) * NN + row0 + hf * 64;
#pragma unroll
        for (int k = 0; k < 8; ++k)
            *(uint4*)(dst + k * 8) = *(const uint4*)(src + k * 8);
    }
}

// ---------------- Kernel B: fused attention ----------------
// grid (256, 8), block 256 (4 waves). 16 q-rows per block; each wave owns a
// 1024-wide k-slice for both passes. Swapped MFMA (D = S^T tile): lane (g,li)
// holds q=li, k=jt*16+g*4+r -> contiguous float4 weight stores.
__global__ __launch_bounds__(256) void attn_kernel(
    const ushort* __restrict__ Qb, const ushort* __restrict__ Kb,
    const ushort* __restrict__ Vt,
    float* __restrict__ wout, float* __restrict__ att)
{
    const int h = blockIdx.y;
    const int row0 = blockIdx.x * 16;
    const int tid = threadIdx.x;
    const int w = tid >> 6, lane = tid & 63;
    const int g = lane >> 4, li = lane & 15;

    const ushort* Qh = Qb + (size_t)h * NN * HD;
    const ushort* Kh = Kb + (size_t)h * NN * HD;
    const ushort* Vh = Vt + (size_t)h * HD * NN;
    float* WH = wout + ((size_t)h << 24);

    // per-wave 4352B region: used as P-staging (first 2KB) during the loop,
    // then as attred[16][68] f32 for the cross-wave PV reduction.
    __shared__ __align__(16) char smem[4 * 4352];
    __shared__ float zpart[4][16];

    char* myp = smem + w * 4352;

    // Q fragment (B-operand): lane (g,li) -> Q[row0+li][g*8+j]
    const short8 qa0 = *(const short8*)(Qh + (size_t)(row0 + li) * HD + g * 8);
    const short8 qa1 = *(const short8*)(Qh + (size_t)(row0 + li) * HD + 32 + g * 8);

    // ---- Pass A: Z over this wave's k-slice ----
    float zsum = 0.f;
#pragma unroll 2
    for (int jt = w * 64; jt < w * 64 + 64; ++jt) {
        const ushort* kp = Kh + (size_t)(jt * 16 + li) * HD + g * 8;
        short8 kb0 = *(const short8*)(kp);
        short8 kb1 = *(const short8*)(kp + 32);
        f32x4 acc = {0.f, 0.f, 0.f, 0.f};
        acc = __builtin_amdgcn_mfma_f32_16x16x32_bf16(kb0, qa0, acc, 0, 0, 0);
        acc = __builtin_amdgcn_mfma_f32_16x16x32_bf16(kb1, qa1, acc, 0, 0, 0);
#pragma unroll
        for (int r = 0; r < 4; ++r) zsum += __expf(acc[r] * 0.125f);
    }
    zsum += __shfl_xor(zsum, 16);
    zsum += __shfl_xor(zsum, 32);
    if (lane < 16) zpart[w][li] = zsum;
    __syncthreads();
    const float iz = 1.0f / (zpart[0][li] + zpart[1][li] + zpart[2][li] + zpart[3][li]);

    // ---- Pass B: weights write + P@V over this wave's k-slice ----
    f32x4 pv[4];
#pragma unroll
    for (int dt = 0; dt < 4; ++dt) pv[dt] = (f32x4){0.f, 0.f, 0.f, 0.f};

    for (int nc = w * 1024; nc < w * 1024 + 1024; nc += 64) {
#pragma unroll
        for (int jj = 0; jj < 4; ++jj) {
            int jt = (nc >> 4) + jj;
            const ushort* kp = Kh + (size_t)(jt * 16 + li) * HD + g * 8;
            short8 kb0 = *(const short8*)(kp);
            short8 kb1 = *(const short8*)(kp + 32);
            f32x4 acc = {0.f, 0.f, 0.f, 0.f};
            acc = __builtin_amdgcn_mfma_f32_16x16x32_bf16(kb0, qa0, acc, 0, 0, 0);
            acc = __builtin_amdgcn_mfma_f32_16x16x32_bf16(kb1, qa1, acc, 0, 0, 0);
            f32x4 ev;
            uint pk[2];
#pragma unroll
            for (int r = 0; r < 4; ++r) ev[r] = __expf(acc[r] * 0.125f) * iz;
            pk[0] = (uint)f2bf(ev[0]) | ((uint)f2bf(ev[1]) << 16);
            pk[1] = (uint)f2bf(ev[2]) | ((uint)f2bf(ev[3]) << 16);
            // contiguous 16B weight store: row q=row0+li, cols jt*16+g*4..+3
            __builtin_nontemporal_store(ev, (f32x4*)(WH + (size_t)(row0 + li) * NN + jt * 16 + g * 4));
            // wave-private LDS P tile [16 q][64 k] bf16, XOR-swizzled
            int boff = (li * 128 + jj * 32 + g * 8) ^ ((li & 7) << 4);
            *(uint2*)(myp + boff) = make_uint2(pk[0], pk[1]);
        }
#pragma unroll
        for (int kb = 0; kb < 2; ++kb) {
            int rb = (li * 128 + kb * 64 + g * 16) ^ ((li & 7) << 4);
            short8 pa = *(const short8*)(myp + rb);
            const ushort* vp = Vh + nc + kb * 32 + g * 8;
#pragma unroll
            for (int dt = 0; dt < 4; ++dt) {
                short8 vb = *(const short8*)(vp + (size_t)(dt * 16 + li) * NN);
                pv[dt] = __builtin_amdgcn_mfma_f32_16x16x32_bf16(pa, vb, pv[dt], 0, 0, 0);
            }
        }
    }

    // ---- cross-wave PV reduction ----
    float* arw = (float*)myp;       // attred[16][68] for this wave
#pragma unroll
    for (int dt = 0; dt < 4; ++dt)
#pragma unroll
        for (int r = 0; r < 4; ++r)
            arw[(g * 4 + r) * 68 + dt * 16 + li] = pv[dt][r];
    __syncthreads();

    {
        const float* ar = (const float*)smem;
        int q = tid >> 4;               // 0..15
        int d0 = (tid & 15) * 4;        // 0..60
        f32x4 s = *(const f32x4*)(ar + 0 * 1088 + q * 68 + d0);
        s += *(const f32x4*)(ar + 1 * 1088 + q * 68 + d0);
        s += *(const f32x4*)(ar + 2 * 1088 + q * 68 + d0);
        s += *(const f32x4*)(ar + 3 * 1088 + q * 68 + d0);
        *(f32x4*)(att + (size_t)(row0 + q) * HID + h * HD + d0) = s;
    }
}

// ---------------- Kernel C: output = att @ Wo + bo ----------------
__global__ __launch_bounds__(256) void out_kernel(
    const float* __restrict__ att, const float* __restrict__ Wo,
    const float* __restrict__ bo, float* __restrict__ outp)
{
    const int row0 = blockIdx.x * 64;
    const int tid = threadIdx.x;
    const int tx = tid & 15, ty = tid >> 4;

    __shared__ float as_[64][68];
    __shared__ float ws2[64][68];

    float acc[4][4];
#pragma unroll
    for (int i = 0; i < 4; ++i)
#pragma unroll
        for (int j = 0; j < 4; ++j) acc[i][j] = 0.f;

    for (int kc = 0; kc < HID; kc += 64) {
#pragma unroll
        for (int it = 0; it < 4; ++it) {
            int f = it * 256 + tid;
            int i = f >> 4, k4 = f & 15;
            float4 v = *(const float4*)(att + (size_t)(row0 + i) * HID + kc + k4 * 4);
            as_[k4 * 4 + 0][i] = v.x; as_[k4 * 4 + 1][i] = v.y;
            as_[k4 * 4 + 2][i] = v.z; as_[k4 * 4 + 3][i] = v.w;
        }
#pragma unroll
        for (int it = 0; it < 4; ++it) {
            int f = it * 256 + tid;
            int k = f >> 4, c4 = f & 15;
            float4 v = *(const float4*)(Wo + (size_t)(kc + k) * HD + c4 * 4);
            *(float4*)&ws2[k][c4 * 4] = v;
        }
        __syncthreads();
        for (int k = 0; k < 64; ++k) {
            float a0[4], b0[4];
            *(float4*)&a0[0] = *(const float4*)&as_[k][ty * 4];
            *(float4*)&b0[0] = *(const float4*)&ws2[k][tx * 4];
#pragma unroll
            for (int i = 0; i < 4; ++i)
#pragma unroll
                for (int j = 0; j < 4; ++j)
                    acc[i][j] = fmaf(a0[i], b0[j], acc[i][j]);
        }
        __syncthreads();
    }

#pragma unroll
    for (int ii = 0; ii < 4; ++ii) {
        int r = row0 + ty * 4 + ii;
        float4 v;
        v.x = acc[ii][0] + bo[tx * 4 + 0];
        v.y = acc[ii][1] + bo[tx * 4 + 1];
        v.z = acc[ii][2] + bo[tx * 4 + 2];
        v.w = acc[ii][3] + bo[tx * 4 + 3];
        *(float4*)(outp + (size_t)r * HD + tx * 4) = v;
    }
}

extern "C" void kernel_launch(void* const* d_in, const int* in_sizes, int n_in,
                              void* d_out, int out_size, void* d_ws, size_t ws_size,
                              hipStream_t stream) {
    const float* x  = (const float*)d_in[0];
    const float* Wq = (const float*)d_in[1];
    const float* bq = (const float*)d_in[2];
    const float* Wk = (const float*)d_in[3];
    const float* bk = (const float*)d_in[4];
    const float* Wv = (const float*)d_in[5];
    const float* bv = (const float*)d_in[6];
    const float* Wo = (const float*)d_in[7];
    const float* bo = (const float*)d_in[8];

    float* out  = (float*)d_out;
    float* wout = out + (size_t)NN * HD;      // attention-weights output region

    char* wsb = (char*)d_ws;
    ushort* Qb = (ushort*)wsb;                           // 4 MB
    ushort* Kb = Qb + (size_t)NH * NN * HD;              // 4 MB
    ushort* Vt = Kb + (size_t)NH * NN * HD;              // 4 MB
    float*  att = (float*)(wsb + 12u * 1024u * 1024u);   // 8 MB

    hipLaunchKernelGGL(qkv_kernel, dim3(4, 32, 3), dim3(256), 0, stream,
                       x, Wq, bq, Wk, bk, Wv, bv, Qb, Kb, Vt);
    hipLaunchKernelGGL(attn_kernel, dim3(256, NH), dim3(256), 0, stream,
                       Qb, Kb, Vt, wout, att);
    hipLaunchKernelGGL(out_kernel, dim3(64), dim3(256), 0, stream,
                       att, Wo, bo, out);
}

// Round 4
// 473.383 us; speedup vs baseline: 1.9807x; 1.0091x over previous
//
#include <hip/hip_runtime.h>

#define NN 4096
#define HID 512
#define NH 8
#define HD 64

typedef __attribute__((ext_vector_type(8))) short short8;
typedef __attribute__((ext_vector_type(4))) float f32x4;

__device__ __forceinline__ ushort f2bf(float f) {
    unsigned u = __float_as_uint(f);
    return (ushort)((u + 0x7FFFu + ((u >> 16) & 1u)) >> 16);   // RNE
}

// ---------------- Kernel A: QKV projection (f32 compute, bf16 output) -----------------
__global__ __launch_bounds__(256) void qkv_kernel(
    const float* __restrict__ x,
    const float* __restrict__ Wq, const float* __restrict__ bq,
    const float* __restrict__ Wk, const float* __restrict__ bk,
    const float* __restrict__ Wv, const float* __restrict__ bv,
    ushort* __restrict__ Qb, ushort* __restrict__ Kb, ushort* __restrict__ Vt)
{
    const int mat = blockIdx.z;
    const float* W = (mat == 0) ? Wq : ((mat == 1) ? Wk : Wv);
    const float* b = (mat == 0) ? bq : ((mat == 1) ? bk : bv);

    const int row0 = blockIdx.y * 128;
    const int col0 = blockIdx.x * 128;
    const int tid = threadIdx.x;
    const int tx = tid & 15, ty = tid >> 4;

    __shared__ float xs[32][132];
    __shared__ float wt[32][132];
    __shared__ __align__(16) ushort vts[128][136];

    float acc[8][8];
#pragma unroll
    for (int i = 0; i < 8; ++i)
#pragma unroll
        for (int j = 0; j < 8; ++j) acc[i][j] = 0.f;

    for (int kc = 0; kc < HID; kc += 32) {
#pragma unroll
        for (int it = 0; it < 4; ++it) {
            int f = it * 256 + tid;
            int i = f >> 3, k4 = f & 7;
            float4 v = *(const float4*)(x + (size_t)(row0 + i) * HID + kc + k4 * 4);
            xs[k4 * 4 + 0][i] = v.x; xs[k4 * 4 + 1][i] = v.y;
            xs[k4 * 4 + 2][i] = v.z; xs[k4 * 4 + 3][i] = v.w;
        }
#pragma unroll
        for (int it = 0; it < 4; ++it) {
            int f = it * 256 + tid;
            int k = f >> 5, c4 = f & 31;
            float4 v = *(const float4*)(W + (size_t)(kc + k) * HID + col0 + c4 * 4);
            *(float4*)&wt[k][c4 * 4] = v;
        }
        __syncthreads();
        for (int k = 0; k < 32; ++k) {
            float a0[8], b0[8];
            *(float4*)&a0[0] = *(const float4*)&xs[k][ty * 4];
            *(float4*)&a0[4] = *(const float4*)&xs[k][64 + ty * 4];
            *(float4*)&b0[0] = *(const float4*)&wt[k][tx * 4];
            *(float4*)&b0[4] = *(const float4*)&wt[k][64 + tx * 4];
#pragma unroll
            for (int i = 0; i < 8; ++i)
#pragma unroll
                for (int j = 0; j < 8; ++j)
                    acc[i][j] = fmaf(a0[i], b0[j], acc[i][j]);
        }
        __syncthreads();
    }

    if (mat < 2) {
        ushort* O = (mat == 0) ? Qb : Kb;
#pragma unroll
        for (int bi = 0; bi < 2; ++bi)
#pragma unroll
            for (int ii = 0; ii < 4; ++ii) {
                int r = row0 + bi * 64 + ty * 4 + ii;
#pragma unroll
                for (int bj = 0; bj < 2; ++bj) {
                    int c = col0 + bj * 64 + tx * 4;
                    ushort4 u;
                    u.x = f2bf(acc[bi * 4 + ii][bj * 4 + 0] + b[c + 0]);
                    u.y = f2bf(acc[bi * 4 + ii][bj * 4 + 1] + b[c + 1]);
                    u.z = f2bf(acc[bi * 4 + ii][bj * 4 + 2] + b[c + 2]);
                    u.w = f2bf(acc[bi * 4 + ii][bj * 4 + 3] + b[c + 3]);
                    *(ushort4*)(O + ((size_t)(c >> 6) * NN + r) * HD + (c & 63)) = u;
                }
            }
    } else {
#pragma unroll
        for (int bi = 0; bi < 2; ++bi)
#pragma unroll
            for (int ii = 0; ii < 4; ++ii) {
                int rl = bi * 64 + ty * 4 + ii;
#pragma unroll
                for (int bj = 0; bj < 2; ++bj)
#pragma unroll
                    for (int j = 0; j < 4; ++j) {
                        int cl = bj * 64 + tx * 4 + j;
                        vts[cl][rl] = f2bf(acc[bi * 4 + ii][bj * 4 + j] + b[col0 + cl]);
                    }
            }
        __syncthreads();
        int cl = tid >> 1, hf = tid & 1;
        const ushort* src = &vts[cl][hf * 64];
        ushort* dst = Vt + (size_t)(col0 + cl) * NN + row0 + hf * 64;
#pragma unroll
        for (int k = 0; k < 8; ++k)
            *(uint4*)(dst + k * 8) = *(const uint4*)(src + k * 8);
    }
}

// ---------------- Kernel B: fused attention ----------------
// grid (256, 8), block 256 (4 waves). 16 q-rows/block, wave-sliced k (1024 each).
// Swapped MFMA (D = S^T): lane (g,li) holds q=li, k=jt*16+g*4+r.
// Weights staged per-wave in LDS (16x64 f32, XOR-swizzled), flushed as
// 256B-contiguous row runs (4 wide store instrs per 64-col chunk).
__global__ __launch_bounds__(256) void attn_kernel(
    const ushort* __restrict__ Qb, const ushort* __restrict__ Kb,
    const ushort* __restrict__ Vt,
    float* __restrict__ wout, float* __restrict__ att)
{
    const int h = blockIdx.y;
    const int row0 = blockIdx.x * 16;
    const int tid = threadIdx.x;
    const int w = tid >> 6, lane = tid & 63;
    const int g = lane >> 4, li = lane & 15;

    const ushort* Qh = Qb + (size_t)h * NN * HD;
    const ushort* Kh = Kb + (size_t)h * NN * HD;
    const ushort* Vh = Vt + (size_t)h * HD * NN;
    float* WH = wout + ((size_t)h << 24);

    // per-wave 6144B region:
    //   [0,4096)    f32 weight staging 16x64, XOR-swizzled
    //   [4096,6144) bf16 P tile 16x64, XOR-swizzled
    //   after loop: attred f32[16][68] overlays [0,4352)
    __shared__ __align__(16) char smem[4 * 6144];
    __shared__ float zpart[4][16];

    char* myp = smem + w * 6144;

    const short8 qa0 = *(const short8*)(Qh + (size_t)(row0 + li) * HD + g * 8);
    const short8 qa1 = *(const short8*)(Qh + (size_t)(row0 + li) * HD + 32 + g * 8);

    // ---- Pass A: Z over this wave's k-slice ----
    float zsum = 0.f;
#pragma unroll 2
    for (int jt = w * 64; jt < w * 64 + 64; ++jt) {
        const ushort* kp = Kh + (size_t)(jt * 16 + li) * HD + g * 8;
        short8 kb0 = *(const short8*)(kp);
        short8 kb1 = *(const short8*)(kp + 32);
        f32x4 acc = {0.f, 0.f, 0.f, 0.f};
        acc = __builtin_amdgcn_mfma_f32_16x16x32_bf16(kb0, qa0, acc, 0, 0, 0);
        acc = __builtin_amdgcn_mfma_f32_16x16x32_bf16(kb1, qa1, acc, 0, 0, 0);
#pragma unroll
        for (int r = 0; r < 4; ++r) zsum += __expf(acc[r] * 0.125f);
    }
    zsum += __shfl_xor(zsum, 16);
    zsum += __shfl_xor(zsum, 32);
    if (lane < 16) zpart[w][li] = zsum;
    __syncthreads();
    const float iz = 1.0f / (zpart[0][li] + zpart[1][li] + zpart[2][li] + zpart[3][li]);

    // ---- Pass B ----
    f32x4 pv[4];
#pragma unroll
    for (int dt = 0; dt < 4; ++dt) pv[dt] = (f32x4){0.f, 0.f, 0.f, 0.f};

    for (int nc = w * 1024; nc < w * 1024 + 1024; nc += 64) {
#pragma unroll
        for (int jj = 0; jj < 4; ++jj) {
            int jt = (nc >> 4) + jj;
            const ushort* kp = Kh + (size_t)(jt * 16 + li) * HD + g * 8;
            short8 kb0 = *(const short8*)(kp);
            short8 kb1 = *(const short8*)(kp + 32);
            f32x4 acc = {0.f, 0.f, 0.f, 0.f};
            acc = __builtin_amdgcn_mfma_f32_16x16x32_bf16(kb0, qa0, acc, 0, 0, 0);
            acc = __builtin_amdgcn_mfma_f32_16x16x32_bf16(kb1, qa1, acc, 0, 0, 0);
            f32x4 ev;
#pragma unroll
            for (int r = 0; r < 4; ++r) ev[r] = __expf(acc[r] * 0.125f) * iz;
            // f32 staging write: row li, col-bytes jj*64+g*16
            int so = (li * 256 + jj * 64 + g * 16) ^ ((li & 7) << 4);
            *(f32x4*)(myp + so) = ev;
            // bf16 P tile
            uint pk0 = (uint)f2bf(ev[0]) | ((uint)f2bf(ev[1]) << 16);
            uint pk1 = (uint)f2bf(ev[2]) | ((uint)f2bf(ev[3]) << 16);
            int boff = 4096 + ((li * 128 + jj * 32 + g * 8) ^ ((li & 7) << 4));
            *(uint2*)(myp + boff) = make_uint2(pk0, pk1);
        }
        // flush staging: 4 instrs, each = 4 rows x 256B contiguous
#pragma unroll
        for (int i = 0; i < 4; ++i) {
            int r = i * 4 + g;
            int ro = (r * 256 + li * 16) ^ ((r & 7) << 4);
            f32x4 val = *(const f32x4*)(myp + ro);
            __builtin_nontemporal_store(val,
                (f32x4*)(WH + (size_t)(row0 + r) * NN + nc + li * 4));
        }
        // PV
#pragma unroll
        for (int kb = 0; kb < 2; ++kb) {
            int rb = 4096 + ((li * 128 + kb * 64 + g * 16) ^ ((li & 7) << 4));
            short8 pa = *(const short8*)(myp + rb);
            const ushort* vp = Vh + nc + kb * 32 + g * 8;
#pragma unroll
            for (int dt = 0; dt < 4; ++dt) {
                short8 vb = *(const short8*)(vp + (size_t)(dt * 16 + li) * NN);
                pv[dt] = __builtin_amdgcn_mfma_f32_16x16x32_bf16(pa, vb, pv[dt], 0, 0, 0);
            }
        }
    }

    // ---- cross-wave PV reduction (attred overlays staging) ----
    float* arw = (float*)myp;
#pragma unroll
    for (int dt = 0; dt < 4; ++dt)
#pragma unroll
        for (int r = 0; r < 4; ++r)
            arw[(g * 4 + r) * 68 + dt * 16 + li] = pv[dt][r];
    __syncthreads();

    {
        int q = tid >> 4;
        int d0 = (tid & 15) * 4;
        f32x4 s = *(const f32x4*)((const float*)(smem + 0 * 6144) + q * 68 + d0);
        s += *(const f32x4*)((const float*)(smem + 1 * 6144) + q * 68 + d0);
        s += *(const f32x4*)((const float*)(smem + 2 * 6144) + q * 68 + d0);
        s += *(const f32x4*)((const float*)(smem + 3 * 6144) + q * 68 + d0);
        *(f32x4*)(att + (size_t)(row0 + q) * HID + h * HD + d0) = s;
    }
}

// ---------------- Kernel C: output = att @ Wo + bo ----------------
__global__ __launch_bounds__(256) void out_kernel(
    const float* __restrict__ att, const float* __restrict__ Wo,
    const float* __restrict__ bo, float* __restrict__ outp)
{
    const int row0 = blockIdx.x * 64;
    const int tid = threadIdx.x;
    const int tx = tid & 15, ty = tid >> 4;

    __shared__ float as_[64][68];
    __shared__ float ws2[64][68];

    float acc[4][4];
#pragma unroll
    for (int i = 0; i < 4; ++i)
#pragma unroll
        for (int j = 0; j < 4; ++j) acc[i][j] = 0.f;

    for (int kc = 0; kc < HID; kc += 64) {
#pragma unroll
        for (int it = 0; it < 4; ++it) {
            int f = it * 256 + tid;
            int i = f >> 4, k4 = f & 15;
            float4 v = *(const float4*)(att + (size_t)(row0 + i) * HID + kc + k4 * 4);
            as_[k4 * 4 + 0][i] = v.x; as_[k4 * 4 + 1][i] = v.y;
            as_[k4 * 4 + 2][i] = v.z; as_[k4 * 4 + 3][i] = v.w;
        }
#pragma unroll
        for (int it = 0; it < 4; ++it) {
            int f = it * 256 + tid;
            int k = f >> 4, c4 = f & 15;
            float4 v = *(const float4*)(Wo + (size_t)(kc + k) * HD + c4 * 4);
            *(float4*)&ws2[k][c4 * 4] = v;
        }
        __syncthreads();
        for (int k = 0; k < 64; ++k) {
            float a0[4], b0[4];
            *(float4*)&a0[0] = *(const float4*)&as_[k][ty * 4];
            *(float4*)&b0[0] = *(const float4*)&ws2[k][tx * 4];
#pragma unroll
            for (int i = 0; i < 4; ++i)
#pragma unroll
                for (int j = 0; j < 4; ++j)
                    acc[i][j] = fmaf(a0[i], b0[j], acc[i][j]);
        }
        __syncthreads();
    }

#pragma unroll
    for (int ii = 0; ii < 4; ++ii) {
        int r = row0 + ty * 4 + ii;
        float4 v;
        v.x = acc[ii][0] + bo[tx * 4 + 0];
        v.y = acc[ii][1] + bo[tx * 4 + 1];
        v.z = acc[ii][2] + bo[tx * 4 + 2];
        v.w = acc[ii][3] + bo[tx * 4 + 3];
        *(float4*)(outp + (size_t)r * HD + tx * 4) = v;
    }
}

extern "C" void kernel_launch(void* const* d_in, const int* in_sizes, int n_in,
                              void* d_out, int out_size, void* d_ws, size_t ws_size,
                              hipStream_t stream) {
    const float* x  = (const float*)d_in[0];
    const float* Wq = (const float*)d_in[1];
    const float* bq = (const float*)d_in[2];
    const float* Wk = (const float*)d_in[3];
    const float* bk = (const float*)d_in[4];
    const float* Wv = (const float*)d_in[5];
    const float* bv = (const float*)d_in[6];
    const float* Wo = (const float*)d_in[7];
    const float* bo = (const float*)d_in[8];

    float* out  = (float*)d_out;
    float* wout = out + (size_t)NN * HD;

    char* wsb = (char*)d_ws;
    ushort* Qb = (ushort*)wsb;
    ushort* Kb = Qb + (size_t)NH * NN * HD;
    ushort* Vt = Kb + (size_t)NH * NN * HD;
    float*  att = (float*)(wsb + 12u * 1024u * 1024u);

    hipLaunchKernelGGL(qkv_kernel, dim3(4, 32, 3), dim3(256), 0, stream,
                       x, Wq, bq, Wk, bk, Wv, bv, Qb, Kb, Vt);
    hipLaunchKernelGGL(attn_kernel, dim3(256, NH), dim3(256), 0, stream,
                       Qb, Kb, Vt, wout, att);
    hipLaunchKernelGGL(out_kernel, dim3(64), dim3(256), 0, stream,
                       att, Wo, bo, out);
}